// Round 1
// baseline (4173.931 us; speedup 1.0000x reference)
//
#include <hip/hip_runtime.h>

#define N_    8
#define H_    32
#define W_    32
#define C_    768
#define NH_   12
#define HD_   64
#define B_    96      // N_*NH_
#define HW_   1024
#define C3_   2304
#define SCALE_ 0.125f

// ---------------------------------------------------------------------------
// Kernel 1: qkv = x @ w_qkv + b_qkv, scattered into q/k/v (B, HW, HD) fp32.
// A: (8192, 768) row-major (= x). B: (768, 2304) row-major.
// 64x64 tile, BK=16, 256 threads, 4x4 microtile per thread.
// ---------------------------------------------------------------------------
__global__ __launch_bounds__(256) void qkv_gemm(const float* __restrict__ x,
                                                const float* __restrict__ w,
                                                const float* __restrict__ bias,
                                                float* __restrict__ q,
                                                float* __restrict__ k,
                                                float* __restrict__ v) {
    __shared__ float As[16][64];
    __shared__ float Bs[16][64];
    const int t = threadIdx.x;
    const int nbase = blockIdx.x * 64;   // column in [0, 2304)
    const int mbase = blockIdx.y * 64;   // row in [0, 8192)
    const int tx = t & 15, ty = t >> 4;
    float acc[4][4] = {};

    for (int kb = 0; kb < C_; kb += 16) {
        // A tile: 64 rows x 16 k. thread t loads float4 at (m_local=t>>2, kq=(t&3)*4)
        {
            const int ml = t >> 2;
            const int kq = (t & 3) * 4;
            float4 a = *(const float4*)(x + (size_t)(mbase + ml) * C_ + kb + kq);
            As[kq + 0][ml] = a.x;
            As[kq + 1][ml] = a.y;
            As[kq + 2][ml] = a.z;
            As[kq + 3][ml] = a.w;
        }
        // B tile: 16 k x 64 n. thread t loads float4 at (kr=t>>4, nn=(t&15)*4)
        {
            const int kr = t >> 4;
            const int nn = (t & 15) * 4;
            float4 b = *(const float4*)(w + (size_t)(kb + kr) * C3_ + nbase + nn);
            *(float4*)(&Bs[kr][nn]) = b;
        }
        __syncthreads();
        #pragma unroll
        for (int kk = 0; kk < 16; ++kk) {
            float ra[4], rb[4];
            #pragma unroll
            for (int i = 0; i < 4; ++i) ra[i] = As[kk][ty * 4 + i];
            #pragma unroll
            for (int j = 0; j < 4; ++j) rb[j] = Bs[kk][tx * 4 + j];
            #pragma unroll
            for (int i = 0; i < 4; ++i)
                #pragma unroll
                for (int j = 0; j < 4; ++j) acc[i][j] += ra[i] * rb[j];
        }
        __syncthreads();
    }

    // nbase is 64-aligned -> which third and head are constant per block
    const int which = nbase / C_;             // 0=q, 1=k, 2=v
    const int head  = (nbase % C_) >> 6;      // 0..11
    float* dst = (which == 0) ? q : ((which == 1) ? k : v);
    #pragma unroll
    for (int i = 0; i < 4; ++i) {
        const int m = mbase + ty * 4 + i;
        const int n_img = m >> 10;            // 0..7
        const int p     = m & 1023;           // 0..1023
        #pragma unroll
        for (int j = 0; j < 4; ++j) {
            const int col = nbase + tx * 4 + j;
            const int d   = col & 63;
            dst[((size_t)(n_img * NH_ + head) * HW_ + p) * HD_ + d] = acc[i][j] + bias[col];
        }
    }
}

// ---------------------------------------------------------------------------
// Kernel 2: attention for one (b, 16-row q tile).
// S row (16x1024) lives in LDS; two-pass softmax; PV with register acc.
// Dynamic LDS: sQ(1024) + sKV(2048) + sBH(512) + sBW(512) + sS(16384) floats
//            = 20480 floats = 80 KiB.
// ---------------------------------------------------------------------------
__global__ __launch_bounds__(256) void attn_kernel(const float* __restrict__ q,
                                                   const float* __restrict__ k,
                                                   const float* __restrict__ v,
                                                   const float* __restrict__ rel_h,
                                                   const float* __restrict__ rel_w,
                                                   float* __restrict__ o) {
    extern __shared__ float smem[];
    float* sQ  = smem;            // 16*64
    float* sKV = smem + 1024;     // 32*64
    float* sBH = smem + 3072;     // 16*32
    float* sBW = smem + 3584;     // 16*32
    float* sS  = smem + 4096;     // 16*1024

    const int t = threadIdx.x;
    const int b = blockIdx.y;
    const int qbase = blockIdx.x * 16;
    const int hq = qbase >> 5;                 // constant over the 16-row tile

    // load Q tile (1024 floats)
    *(float4*)(sQ + t * 4) = *(const float4*)(q + ((size_t)b * HW_ + qbase) * HD_ + t * 4);
    __syncthreads();

    // rel-pos bias tables: bh[row][kh], bw[row][kw]  (16x32 each)
    for (int oid = t; oid < 1024; oid += 256) {
        const int table = oid >> 9;       // 0 = bh, 1 = bw
        const int rem = oid & 511;
        const int row = rem >> 5;
        const int j   = rem & 31;
        const float* qv = sQ + row * 64;
        const float* rp;
        if (table == 0) {
            rp = rel_h + (size_t)(hq - j + 31) * HD_;
        } else {
            const int wq = (qbase + row) & 31;
            rp = rel_w + (size_t)(wq - j + 31) * HD_;
        }
        float acc = 0.f;
        #pragma unroll
        for (int d = 0; d < 64; ++d) acc += qv[d] * rp[d];
        if (table == 0) sBH[row * 32 + j] = acc;
        else            sBW[row * 32 + j] = acc;
    }
    __syncthreads();

    // S = scale * q k^T + bias   (loop over 32-wide k tiles)
    for (int kb = 0; kb < 32; ++kb) {
        __syncthreads();
        const float* kp = k + ((size_t)b * HW_ + kb * 32) * HD_;
        *(float4*)(sKV + t * 4)        = *(const float4*)(kp + t * 4);
        *(float4*)(sKV + 1024 + t * 4) = *(const float4*)(kp + 1024 + t * 4);
        __syncthreads();
        int sid = t * 2;
        #pragma unroll
        for (int u = 0; u < 2; ++u, ++sid) {
            const int row = sid >> 5;
            const int kk  = sid & 31;
            const float4* qv = (const float4*)(sQ + row * 64);
            const float4* kv = (const float4*)(sKV + kk * 64);
            float acc = 0.f;
            #pragma unroll
            for (int d4 = 0; d4 < 16; ++d4) {
                float4 a = qv[d4], bb = kv[d4];
                acc += a.x * bb.x + a.y * bb.y + a.z * bb.z + a.w * bb.w;
            }
            sS[row * 1024 + kb * 32 + kk] = acc * SCALE_ + sBH[row * 32 + kb] + sBW[row * 32 + kk];
        }
    }
    __syncthreads();

    // softmax: 16 lanes per row
    {
        const int row = t >> 4, l = t & 15;
        float* srow = sS + row * 1024;
        float m = -1e30f;
        for (int j = l; j < 1024; j += 16) m = fmaxf(m, srow[j]);
        #pragma unroll
        for (int mask = 1; mask < 16; mask <<= 1) m = fmaxf(m, __shfl_xor(m, mask));
        float s = 0.f;
        for (int j = l; j < 1024; j += 16) {
            float e = __expf(srow[j] - m);
            srow[j] = e;
            s += e;
        }
        #pragma unroll
        for (int mask = 1; mask < 16; mask <<= 1) s += __shfl_xor(s, mask);
        const float inv = 1.0f / s;
        for (int j = l; j < 1024; j += 16) srow[j] *= inv;
    }
    __syncthreads();

    // PV: thread owns (row = t>>4, d4 = (t&15)*4)
    {
        const int row = t >> 4;
        const int dq  = (t & 15) * 4;
        float a0 = 0.f, a1 = 0.f, a2 = 0.f, a3 = 0.f;
        for (int kb = 0; kb < 32; ++kb) {
            __syncthreads();
            const float* vp = v + ((size_t)b * HW_ + kb * 32) * HD_;
            *(float4*)(sKV + t * 4)        = *(const float4*)(vp + t * 4);
            *(float4*)(sKV + 1024 + t * 4) = *(const float4*)(vp + 1024 + t * 4);
            __syncthreads();
            const float* srow = sS + row * 1024 + kb * 32;
            #pragma unroll
            for (int kk = 0; kk < 32; ++kk) {
                const float p = srow[kk];
                const float4 vv = *(const float4*)(sKV + kk * 64 + dq);
                a0 += p * vv.x; a1 += p * vv.y; a2 += p * vv.z; a3 += p * vv.w;
            }
        }
        float4 res = make_float4(a0, a1, a2, a3);
        *(float4*)(o + ((size_t)b * HW_ + qbase + row) * HD_ + dq) = res;
    }
}

// ---------------------------------------------------------------------------
// Kernel 3: out = attn_out @ w_proj + b_proj.
// attn_out logical (8192, 768): A'[m][c] = o[((m>>10)*12 + (c>>6))*HW*HD + (m&1023)*64 + (c&63)]
// ---------------------------------------------------------------------------
__global__ __launch_bounds__(256) void proj_gemm(const float* __restrict__ o,
                                                 const float* __restrict__ w,
                                                 const float* __restrict__ bias,
                                                 float* __restrict__ out) {
    __shared__ float As[16][64];
    __shared__ float Bs[16][64];
    const int t = threadIdx.x;
    const int nbase = blockIdx.x * 64;   // 0..767
    const int mbase = blockIdx.y * 64;   // 0..8191
    const int tx = t & 15, ty = t >> 4;
    float acc[4][4] = {};

    for (int kb = 0; kb < C_; kb += 16) {
        {
            const int ml = t >> 2;
            const int kq = (t & 3) * 4;
            const int m = mbase + ml;
            const int kidx = kb + kq;
            const int n_img = m >> 10, p = m & 1023;
            const int head = kidx >> 6, d = kidx & 63;
            float4 a = *(const float4*)(o + ((size_t)(n_img * NH_ + head) * HW_ + p) * HD_ + d);
            As[kq + 0][ml] = a.x;
            As[kq + 1][ml] = a.y;
            As[kq + 2][ml] = a.z;
            As[kq + 3][ml] = a.w;
        }
        {
            const int kr = t >> 4;
            const int nn = (t & 15) * 4;
            float4 b = *(const float4*)(w + (size_t)(kb + kr) * C_ + nbase + nn);
            *(float4*)(&Bs[kr][nn]) = b;
        }
        __syncthreads();
        #pragma unroll
        for (int kk = 0; kk < 16; ++kk) {
            float ra[4], rb[4];
            #pragma unroll
            for (int i = 0; i < 4; ++i) ra[i] = As[kk][ty * 4 + i];
            #pragma unroll
            for (int j = 0; j < 4; ++j) rb[j] = Bs[kk][tx * 4 + j];
            #pragma unroll
            for (int i = 0; i < 4; ++i)
                #pragma unroll
                for (int j = 0; j < 4; ++j) acc[i][j] += ra[i] * rb[j];
        }
        __syncthreads();
    }

    #pragma unroll
    for (int i = 0; i < 4; ++i) {
        const int m = mbase + ty * 4 + i;
        #pragma unroll
        for (int j = 0; j < 4; ++j) {
            const int col = nbase + tx * 4 + j;
            out[(size_t)m * C_ + col] = acc[i][j] + bias[col];
        }
    }
}

extern "C" void kernel_launch(void* const* d_in, const int* in_sizes, int n_in,
                              void* d_out, int out_size, void* d_ws, size_t ws_size,
                              hipStream_t stream) {
    const float* x      = (const float*)d_in[0];
    const float* w_qkv  = (const float*)d_in[1];
    const float* b_qkv  = (const float*)d_in[2];
    const float* w_proj = (const float*)d_in[3];
    const float* b_proj = (const float*)d_in[4];
    const float* rel_h  = (const float*)d_in[5];
    const float* rel_w  = (const float*)d_in[6];
    float* out = (float*)d_out;

    float* ws = (float*)d_ws;
    const size_t seg = (size_t)B_ * HW_ * HD_;   // 6,291,456 floats
    float* q = ws;
    float* k = ws + seg;
    float* v = ws + 2 * seg;
    float* o = ws + 3 * seg;

    qkv_gemm<<<dim3(C3_ / 64, 8192 / 64), 256, 0, stream>>>(x, w_qkv, b_qkv, q, k, v);
    attn_kernel<<<dim3(HW_ / 16, B_), 256, 20480 * sizeof(float), stream>>>(q, k, v, rel_h, rel_w, o);
    proj_gemm<<<dim3(C_ / 64, 8192 / 64), 256, 0, stream>>>(o, w_proj, b_proj, out);
}

// Round 2
// 772.207 us; speedup vs baseline: 5.4052x; 5.4052x over previous
//
#include <hip/hip_runtime.h>
#include <hip/hip_bf16.h>

#define N_    8
#define H_    32
#define W_    32
#define C_    768
#define NH_   12
#define HD_   64
#define B_    96      // N_*NH_
#define HW_   1024
#define C3_   2304
#define SCALE_ 0.125f

typedef __attribute__((ext_vector_type(4))) float f32x4;
typedef __attribute__((ext_vector_type(8))) short s16x8;
typedef unsigned short u16;

__device__ inline u16 f2b(float x) {
    __hip_bfloat16 h = __float2bfloat16(x);
    return *reinterpret_cast<u16*>(&h);
}

// ---------------------------------------------------------------------------
// Kernel 1: qkv = x @ w_qkv + b_qkv.
// Epilogue scatters: q -> fp32 [b][p][64], k -> bf16 [b][p][64],
//                    v -> bf16 TRANSPOSED [b][64][p].
// ---------------------------------------------------------------------------
__global__ __launch_bounds__(256) void qkv_gemm(const float* __restrict__ x,
                                                const float* __restrict__ w,
                                                const float* __restrict__ bias,
                                                float* __restrict__ qout,
                                                u16* __restrict__ kout,
                                                u16* __restrict__ vout) {
    __shared__ float As[16][64];
    __shared__ float Bs[16][64];
    const int t = threadIdx.x;
    const int nbase = blockIdx.x * 64;   // column in [0, 2304)
    const int mbase = blockIdx.y * 64;   // row in [0, 8192)
    const int tx = t & 15, ty = t >> 4;
    float acc[4][4] = {};

    for (int kb = 0; kb < C_; kb += 16) {
        {
            const int ml = t >> 2;
            const int kq = (t & 3) * 4;
            float4 a = *(const float4*)(x + (size_t)(mbase + ml) * C_ + kb + kq);
            As[kq + 0][ml] = a.x;
            As[kq + 1][ml] = a.y;
            As[kq + 2][ml] = a.z;
            As[kq + 3][ml] = a.w;
        }
        {
            const int kr = t >> 4;
            const int nn = (t & 15) * 4;
            float4 b = *(const float4*)(w + (size_t)(kb + kr) * C3_ + nbase + nn);
            *(float4*)(&Bs[kr][nn]) = b;
        }
        __syncthreads();
        #pragma unroll
        for (int kk = 0; kk < 16; ++kk) {
            float ra[4], rb[4];
            #pragma unroll
            for (int i = 0; i < 4; ++i) ra[i] = As[kk][ty * 4 + i];
            #pragma unroll
            for (int j = 0; j < 4; ++j) rb[j] = Bs[kk][tx * 4 + j];
            #pragma unroll
            for (int i = 0; i < 4; ++i)
                #pragma unroll
                for (int j = 0; j < 4; ++j) acc[i][j] += ra[i] * rb[j];
        }
        __syncthreads();
    }

    const int which = nbase / C_;             // 0=q, 1=k, 2=v
    const int head  = (nbase % C_) >> 6;      // 0..11
    #pragma unroll
    for (int i = 0; i < 4; ++i) {
        const int m = mbase + ty * 4 + i;
        const int n_img = m >> 10;
        const int p     = m & 1023;
        const size_t bidx = (size_t)(n_img * NH_ + head);
        #pragma unroll
        for (int j = 0; j < 4; ++j) {
            const int col = nbase + tx * 4 + j;
            const int d   = col & 63;
            const float val = acc[i][j] + bias[col];
            if (which == 0) {
                qout[(bidx * HW_ + p) * HD_ + d] = val;
            } else if (which == 1) {
                kout[(bidx * HW_ + p) * HD_ + d] = f2b(val);
            } else {
                vout[bidx * (size_t)(HW_ * HD_) + (size_t)d * HW_ + p] = f2b(val);
            }
        }
    }
}

// ---------------------------------------------------------------------------
// Kernel 2: MFMA bf16 flash-style rel-pos attention.
// Block = 256 threads = 4 waves; 64 q-rows of one b; K/V iterated in 64-tiles.
// Max-free softmax (logits ~ +-2): accumulate exp() and P*V unnormalized,
// divide by row-sum at the end. fp32 accumulation throughout.
// LDS map (bytes):
//   sQ  bf16 [64][72]   @ 0      (9216)
//   sK  bf16 [64][72]   @ 9216   (9216)
//   sVt bf16 [64][72]   @ 18432  (9216)   (rows = d, cols = kv)
//   sBH f32  [64][33]   @ 27648  (8448)
//   sBW f32  [64][33]   @ 36096  (8448)
//   sP  bf16 4x[16][72] @ 44544  (9216)   (wave-private P tiles)
//   qs  f32  [64][68]   @ 9216   (prologue only; overlaps sK/sVt)
// total 53760 B -> 3 blocks/CU.
// ---------------------------------------------------------------------------
__global__ __launch_bounds__(256) void attn_mfma(const float* __restrict__ qf,
                                                 const u16* __restrict__ kbf,
                                                 const u16* __restrict__ vtb,
                                                 const float* __restrict__ rel_h,
                                                 const float* __restrict__ rel_w,
                                                 float* __restrict__ o) {
    extern __shared__ char smem[];
    u16*   sQ  = (u16*)smem;
    u16*   sK  = (u16*)(smem + 9216);
    u16*   sVt = (u16*)(smem + 18432);
    float* sBH = (float*)(smem + 27648);
    float* sBW = (float*)(smem + 36096);
    u16*   sP  = (u16*)(smem + 44544);
    float* qs  = (float*)(smem + 9216);

    const int t = threadIdx.x;
    const int lane = t & 63;
    const int w = t >> 6;
    const int l15 = lane & 15;
    const int lg  = lane >> 4;           // 0..3
    const int wq  = w * 16;              // this wave's q-row base (local)
    const int b = blockIdx.y;
    const int qbase = blockIdx.x * 64;

    // ---- prologue: load Q tile -> qs (fp32) and sQ (bf16)
    {
        const int row = t >> 2;
        const int c0 = (t & 3) * 16;
        const float* src = qf + ((size_t)b * HW_ + qbase + row) * HD_ + c0;
        #pragma unroll
        for (int u = 0; u < 4; ++u) {
            float4 v4 = *(const float4*)(src + u * 4);
            float* qd = qs + row * 68 + c0 + u * 4;
            qd[0] = v4.x; qd[1] = v4.y; qd[2] = v4.z; qd[3] = v4.w;
            u16* qb = sQ + row * 72 + c0 + u * 4;
            qb[0] = f2b(v4.x); qb[1] = f2b(v4.y); qb[2] = f2b(v4.z); qb[3] = f2b(v4.w);
        }
    }
    __syncthreads();

    // ---- rel-pos bias tables (fp32, exact): bh[row][kh], bw[row][kw]
    for (int idv = t; idv < 4096; idv += 256) {
        const int table = idv >> 11;          // 0 = bh, 1 = bw
        const int rem = idv & 2047;
        const int row = rem >> 5;
        const int j   = rem & 31;
        const int qrow = qbase + row;
        const float* rp = (table == 0)
            ? rel_h + (size_t)((qrow >> 5) - j + 31) * HD_
            : rel_w + (size_t)((qrow & 31) - j + 31) * HD_;
        const float* qv = qs + row * 68;
        float acc = 0.f;
        #pragma unroll
        for (int d4 = 0; d4 < 16; ++d4) {
            float4 r4 = *(const float4*)(rp + d4 * 4);
            acc += qv[d4*4+0]*r4.x + qv[d4*4+1]*r4.y + qv[d4*4+2]*r4.z + qv[d4*4+3]*r4.w;
        }
        if (table == 0) sBH[row * 33 + j] = acc;
        else            sBW[row * 33 + j] = acc;
    }
    __syncthreads();   // qs region is dead after this; sK/sVt may be written

    f32x4 Oacc[4] = {};
    float lsum[4] = {0.f, 0.f, 0.f, 0.f};
    u16* sPw = sP + w * (16 * 72);

    for (int kt = 0; kt < 16; ++kt) {
        const int kv0 = kt * 64;
        // ---- stage K tile [64 kv][64 d] and Vt tile [64 d][64 kv]
        {
            const int row = t >> 2;
            const int c0 = (t & 3) * 16;
            const u16* ksrc = kbf + ((size_t)b * HW_ + kv0 + row) * HD_ + c0;
            *(s16x8*)(sK + row * 72 + c0)     = *(const s16x8*)(ksrc);
            *(s16x8*)(sK + row * 72 + c0 + 8) = *(const s16x8*)(ksrc + 8);
            const u16* vsrc = vtb + (size_t)b * (HD_ * HW_) + (size_t)row * HW_ + kv0 + c0;
            *(s16x8*)(sVt + row * 72 + c0)     = *(const s16x8*)(vsrc);
            *(s16x8*)(sVt + row * 72 + c0 + 8) = *(const s16x8*)(vsrc + 8);
        }
        __syncthreads();

        // ---- S-tile = Q K^T (16 q x 64 kv per wave), + bias, exp
        s16x8 qa0 = *(const s16x8*)(sQ + (wq + l15) * 72 + lg * 8);
        s16x8 qa1 = *(const s16x8*)(sQ + (wq + l15) * 72 + lg * 8 + 32);
        float pf[4][4];
        #pragma unroll
        for (int nb = 0; nb < 4; ++nb) {
            s16x8 kb0 = *(const s16x8*)(sK + (nb * 16 + l15) * 72 + lg * 8);
            s16x8 kb1 = *(const s16x8*)(sK + (nb * 16 + l15) * 72 + lg * 8 + 32);
            f32x4 s = {0.f, 0.f, 0.f, 0.f};
            s = __builtin_amdgcn_mfma_f32_16x16x32_bf16(qa0, kb0, s, 0, 0, 0);
            s = __builtin_amdgcn_mfma_f32_16x16x32_bf16(qa1, kb1, s, 0, 0, 0);
            const int kv = kv0 + nb * 16 + l15;   // this lane's kv column
            const int kh = kv >> 5, kw = kv & 31;
            #pragma unroll
            for (int r = 0; r < 4; ++r) {
                const int qrl = wq + lg * 4 + r;  // local q row
                float p = __expf(s[r] * SCALE_ + sBH[qrl * 33 + kh] + sBW[qrl * 33 + kw]);
                lsum[r] += p;
                pf[nb][r] = p;
            }
        }

        // ---- P tile -> wave-private LDS (bf16), transpose to A-frag layout
        #pragma unroll
        for (int nb = 0; nb < 4; ++nb)
            #pragma unroll
            for (int r = 0; r < 4; ++r)
                sPw[(lg * 4 + r) * 72 + nb * 16 + l15] = f2b(pf[nb][r]);
        asm volatile("" ::: "memory");   // same-wave LDS ops execute in order

        // ---- O += P V   (A = P 16x32, B = Vt)
        #pragma unroll
        for (int kvh = 0; kvh < 2; ++kvh) {
            s16x8 pa = *(const s16x8*)(sPw + l15 * 72 + kvh * 32 + lg * 8);
            #pragma unroll
            for (int db = 0; db < 4; ++db) {
                s16x8 vb = *(const s16x8*)(sVt + (db * 16 + l15) * 72 + kvh * 32 + lg * 8);
                Oacc[db] = __builtin_amdgcn_mfma_f32_16x16x32_bf16(pa, vb, Oacc[db], 0, 0, 0);
            }
        }
        __syncthreads();
    }

    // ---- epilogue: row-sum reduce across the 16 kv/d lanes, normalize, store
    #pragma unroll
    for (int r = 0; r < 4; ++r) {
        float s = lsum[r];
        s += __shfl_xor(s, 1);
        s += __shfl_xor(s, 2);
        s += __shfl_xor(s, 4);
        s += __shfl_xor(s, 8);
        lsum[r] = 1.0f / s;
    }
    #pragma unroll
    for (int db = 0; db < 4; ++db) {
        #pragma unroll
        for (int r = 0; r < 4; ++r) {
            const int qg = qbase + wq + lg * 4 + r;
            o[((size_t)b * HW_ + qg) * HD_ + db * 16 + l15] = Oacc[db][r] * lsum[r];
        }
    }
}

// ---------------------------------------------------------------------------
// Kernel 3: out = attn_out @ w_proj + b_proj (fp32, unchanged).
// ---------------------------------------------------------------------------
__global__ __launch_bounds__(256) void proj_gemm(const float* __restrict__ o,
                                                 const float* __restrict__ w,
                                                 const float* __restrict__ bias,
                                                 float* __restrict__ out) {
    __shared__ float As[16][64];
    __shared__ float Bs[16][64];
    const int t = threadIdx.x;
    const int nbase = blockIdx.x * 64;
    const int mbase = blockIdx.y * 64;
    const int tx = t & 15, ty = t >> 4;
    float acc[4][4] = {};

    for (int kb = 0; kb < C_; kb += 16) {
        {
            const int ml = t >> 2;
            const int kq = (t & 3) * 4;
            const int m = mbase + ml;
            const int kidx = kb + kq;
            const int n_img = m >> 10, p = m & 1023;
            const int head = kidx >> 6, d = kidx & 63;
            float4 a = *(const float4*)(o + ((size_t)(n_img * NH_ + head) * HW_ + p) * HD_ + d);
            As[kq + 0][ml] = a.x;
            As[kq + 1][ml] = a.y;
            As[kq + 2][ml] = a.z;
            As[kq + 3][ml] = a.w;
        }
        {
            const int kr = t >> 4;
            const int nn = (t & 15) * 4;
            float4 b = *(const float4*)(w + (size_t)(kb + kr) * C_ + nbase + nn);
            *(float4*)(&Bs[kr][nn]) = b;
        }
        __syncthreads();
        #pragma unroll
        for (int kk = 0; kk < 16; ++kk) {
            float ra[4], rb[4];
            #pragma unroll
            for (int i = 0; i < 4; ++i) ra[i] = As[kk][ty * 4 + i];
            #pragma unroll
            for (int j = 0; j < 4; ++j) rb[j] = Bs[kk][tx * 4 + j];
            #pragma unroll
            for (int i = 0; i < 4; ++i)
                #pragma unroll
                for (int j = 0; j < 4; ++j) acc[i][j] += ra[i] * rb[j];
        }
        __syncthreads();
    }

    #pragma unroll
    for (int i = 0; i < 4; ++i) {
        const int m = mbase + ty * 4 + i;
        #pragma unroll
        for (int j = 0; j < 4; ++j) {
            const int col = nbase + tx * 4 + j;
            out[(size_t)m * C_ + col] = acc[i][j] + bias[col];
        }
    }
}

extern "C" void kernel_launch(void* const* d_in, const int* in_sizes, int n_in,
                              void* d_out, int out_size, void* d_ws, size_t ws_size,
                              hipStream_t stream) {
    const float* x      = (const float*)d_in[0];
    const float* w_qkv  = (const float*)d_in[1];
    const float* b_qkv  = (const float*)d_in[2];
    const float* w_proj = (const float*)d_in[3];
    const float* b_proj = (const float*)d_in[4];
    const float* rel_h  = (const float*)d_in[5];
    const float* rel_w  = (const float*)d_in[6];
    float* out = (float*)d_out;

    float* ws = (float*)d_ws;
    const size_t seg = (size_t)B_ * HW_ * HD_;   // 6,291,456 elements
    float* qfp = ws;                              // fp32
    u16*   kbf = (u16*)(ws + seg);                // bf16 [b][kv][d]
    u16*   vtb = kbf + seg;                       // bf16 [b][d][kv]
    float* o   = (float*)(vtb + seg);             // fp32

    qkv_gemm<<<dim3(C3_ / 64, 8192 / 64), 256, 0, stream>>>(x, w_qkv, b_qkv, qfp, kbf, vtb);
    attn_mfma<<<dim3(HW_ / 64, B_), 256, 53760, stream>>>(qfp, kbf, vtb, rel_h, rel_w, o);
    proj_gemm<<<dim3(C_ / 64, 8192 / 64), 256, 0, stream>>>(o, w_proj, b_proj, out);
}

// Round 3
// 352.610 us; speedup vs baseline: 11.8372x; 2.1900x over previous
//
#include <hip/hip_runtime.h>
#include <hip/hip_bf16.h>

#define N_    8
#define H_    32
#define W_    32
#define C_    768
#define NH_   12
#define HD_   64
#define B_    96      // N_*NH_
#define HW_   1024
#define C3_   2304
#define SCALE_ 0.125f

typedef __attribute__((ext_vector_type(4))) float f32x4;
typedef __attribute__((ext_vector_type(8))) short s16x8;
typedef unsigned short u16;
typedef unsigned int u32;

__device__ inline u16 f2b(float x) {
    __hip_bfloat16 h = __float2bfloat16(x);
    return *reinterpret_cast<u16*>(&h);
}

__device__ __forceinline__ void gld_lds16(const void* g, void* l) {
    __builtin_amdgcn_global_load_lds(
        (const __attribute__((address_space(1))) u32*)g,
        (__attribute__((address_space(3))) u32*)l, 16, 0, 0);
}

// ---------------------------------------------------------------------------
// convert fp32 -> bf16 (vectorized, grid-stride)
// ---------------------------------------------------------------------------
__global__ __launch_bounds__(256) void cvt_bf16(const float* __restrict__ in,
                                                u16* __restrict__ out, int n4) {
    for (int i = blockIdx.x * blockDim.x + threadIdx.x; i < n4; i += gridDim.x * blockDim.x) {
        float4 v = ((const float4*)in)[i];
        ushort4 o;
        o.x = f2b(v.x); o.y = f2b(v.y); o.z = f2b(v.z); o.w = f2b(v.w);
        ((ushort4*)out)[i] = o;
    }
}

// ---------------------------------------------------------------------------
// transpose-convert: in [K][N] fp32 -> out [N][K] bf16, 64x64 tiles
// ---------------------------------------------------------------------------
__global__ __launch_bounds__(256) void tcvt_bf16(const float* __restrict__ in,
                                                 u16* __restrict__ out, int K, int N) {
    __shared__ u16 tile[64][72];
    const int t = threadIdx.x;
    const int k0 = blockIdx.y * 64, n0 = blockIdx.x * 64;
    const int r = t >> 2, c4 = (t & 3) * 16;
    #pragma unroll
    for (int u = 0; u < 4; ++u) {
        float4 v = *(const float4*)(in + (size_t)(k0 + r) * N + n0 + c4 + u * 4);
        tile[c4 + u*4 + 0][r] = f2b(v.x);
        tile[c4 + u*4 + 1][r] = f2b(v.y);
        tile[c4 + u*4 + 2][r] = f2b(v.z);
        tile[c4 + u*4 + 3][r] = f2b(v.w);
    }
    __syncthreads();
    #pragma unroll
    for (int u = 0; u < 2; ++u) {
        s16x8 v;
        #pragma unroll
        for (int e = 0; e < 8; ++e) v[e] = (short)tile[r][c4 + u*8 + e];
        *(s16x8*)(out + (size_t)(n0 + r) * K + k0 + c4 + u*8) = v;
    }
}

// ---------------------------------------------------------------------------
// MFMA GEMM core (m97-style): 128x128 tile, BK=32, 4 waves 2x2, double-buffered
// LDS via global_load_lds width 16, one barrier per K-step. K = 768.
// A [M][768] bf16 row-major; Bt [N][768] bf16 row-major (pre-transposed).
// ---------------------------------------------------------------------------
#define GEMM_CORE(A_, Bt_)                                                           \
    __shared__ u16 sA[2][128 * 32];                                                  \
    __shared__ u16 sB[2][128 * 32];                                                  \
    const int t = threadIdx.x;                                                       \
    const int lane = t & 63;                                                         \
    const int w = t >> 6;                                                            \
    const int wm = w >> 1, wn = w & 1;                                               \
    const int l15 = lane & 15, lg = lane >> 4;                                       \
    const int nbase = blockIdx.x * 128;                                              \
    const int mbase = blockIdx.y * 128;                                              \
    const int srow = lane >> 2;                                                      \
    const int sslot = lane & 3;                                                      \
    const u16* gA0 = (A_) + (size_t)(mbase + w * 16 + srow) * 768 + sslot * 8;       \
    const u16* gA1 = gA0 + (size_t)64 * 768;                                         \
    const u16* gB0 = (Bt_) + (size_t)(nbase + w * 16 + srow) * 768 + sslot * 8;      \
    const u16* gB1 = gB0 + (size_t)64 * 768;                                         \
    f32x4 acc[4][4] = {};                                                            \
    gld_lds16(gA0, &sA[0][w * 512]);                                                 \
    gld_lds16(gA1, &sA[0][(w + 4) * 512]);                                           \
    gld_lds16(gB0, &sB[0][w * 512]);                                                 \
    gld_lds16(gB1, &sB[0][(w + 4) * 512]);                                           \
    for (int kt = 0; kt < 24; ++kt) {                                                \
        const int p = kt & 1;                                                        \
        __syncthreads();                                                             \
        if (kt < 23) {                                                               \
            const int kb = (kt + 1) * 32;                                            \
            gld_lds16(gA0 + kb, &sA[p ^ 1][w * 512]);                                \
            gld_lds16(gA1 + kb, &sA[p ^ 1][(w + 4) * 512]);                          \
            gld_lds16(gB0 + kb, &sB[p ^ 1][w * 512]);                                \
            gld_lds16(gB1 + kb, &sB[p ^ 1][(w + 4) * 512]);                          \
        }                                                                            \
        const u16* pa = &sA[p][(wm * 64 + l15) * 32 + lg * 8];                       \
        const u16* pb = &sB[p][(wn * 64 + l15) * 32 + lg * 8];                       \
        s16x8 afr[4], bfr[4];                                                        \
        _Pragma("unroll")                                                            \
        for (int i = 0; i < 4; ++i) {                                                \
            afr[i] = *(const s16x8*)(pa + i * 512);                                  \
            bfr[i] = *(const s16x8*)(pb + i * 512);                                  \
        }                                                                            \
        _Pragma("unroll")                                                            \
        for (int i = 0; i < 4; ++i)                                                  \
            _Pragma("unroll")                                                        \
            for (int j = 0; j < 4; ++j)                                              \
                acc[i][j] = __builtin_amdgcn_mfma_f32_16x16x32_bf16(afr[i], bfr[j],  \
                                                                    acc[i][j], 0, 0, 0); \
    }

// qkv = x @ w_qkv + b_qkv, scattered: q fp32 [b][p][64], k bf16 [b][p][64],
// v bf16 transposed [b][64][p].
__global__ __launch_bounds__(256) void gemm_qkv(const u16* __restrict__ A,
                                                const u16* __restrict__ Bt,
                                                const float* __restrict__ bias,
                                                float* __restrict__ qout,
                                                u16* __restrict__ kout,
                                                u16* __restrict__ vout) {
    GEMM_CORE(A, Bt)
    const int which = nbase / C_;
    const int head  = ((nbase % C_) >> 6) + wn;
    const int mrow0 = mbase + wm * 64 + lg * 4;
    #pragma unroll
    for (int i = 0; i < 4; ++i) {
        #pragma unroll
        for (int r = 0; r < 4; ++r) {
            const int m = mrow0 + i * 16 + r;
            const size_t bidx = (size_t)((m >> 10) * NH_ + head);
            const int pp = m & 1023;
            #pragma unroll
            for (int j = 0; j < 4; ++j) {
                const int d = j * 16 + l15;
                const float val = acc[i][j][r] + bias[nbase + wn * 64 + d];
                if (which == 0)      qout[(bidx * HW_ + pp) * HD_ + d] = val;
                else if (which == 1) kout[(bidx * HW_ + pp) * HD_ + d] = f2b(val);
                else                 vout[bidx * (size_t)(HW_ * HD_) + (size_t)d * HW_ + pp] = f2b(val);
            }
        }
    }
}

// out = o @ w_proj + b_proj, o bf16 [8192][768], out fp32 [8192][768]
__global__ __launch_bounds__(256) void gemm_proj(const u16* __restrict__ A,
                                                 const u16* __restrict__ Bt,
                                                 const float* __restrict__ bias,
                                                 float* __restrict__ out) {
    GEMM_CORE(A, Bt)
    const int mrow0 = mbase + wm * 64 + lg * 4;
    #pragma unroll
    for (int i = 0; i < 4; ++i) {
        #pragma unroll
        for (int r = 0; r < 4; ++r) {
            const int m = mrow0 + i * 16 + r;
            #pragma unroll
            for (int j = 0; j < 4; ++j) {
                const int n = nbase + wn * 64 + j * 16 + l15;
                out[(size_t)m * C_ + n] = acc[i][j][r] + bias[n];
            }
        }
    }
}

// ---------------------------------------------------------------------------
// Kernel: MFMA bf16 flash-style rel-pos attention (unchanged core; epilogue
// now writes bf16 [m][c] = [8192][768] so proj consumes it directly).
// ---------------------------------------------------------------------------
__global__ __launch_bounds__(256) void attn_mfma(const float* __restrict__ qf,
                                                 const u16* __restrict__ kbf,
                                                 const u16* __restrict__ vtb,
                                                 const float* __restrict__ rel_h,
                                                 const float* __restrict__ rel_w,
                                                 u16* __restrict__ ob) {
    extern __shared__ char smem[];
    u16*   sQ  = (u16*)smem;
    u16*   sK  = (u16*)(smem + 9216);
    u16*   sVt = (u16*)(smem + 18432);
    float* sBH = (float*)(smem + 27648);
    float* sBW = (float*)(smem + 36096);
    u16*   sP  = (u16*)(smem + 44544);
    float* qs  = (float*)(smem + 9216);

    const int t = threadIdx.x;
    const int lane = t & 63;
    const int w = t >> 6;
    const int l15 = lane & 15;
    const int lg  = lane >> 4;
    const int wq  = w * 16;
    const int b = blockIdx.y;
    const int qbase = blockIdx.x * 64;

    {
        const int row = t >> 2;
        const int c0 = (t & 3) * 16;
        const float* src = qf + ((size_t)b * HW_ + qbase + row) * HD_ + c0;
        #pragma unroll
        for (int u = 0; u < 4; ++u) {
            float4 v4 = *(const float4*)(src + u * 4);
            float* qd = qs + row * 68 + c0 + u * 4;
            qd[0] = v4.x; qd[1] = v4.y; qd[2] = v4.z; qd[3] = v4.w;
            u16* qb = sQ + row * 72 + c0 + u * 4;
            qb[0] = f2b(v4.x); qb[1] = f2b(v4.y); qb[2] = f2b(v4.z); qb[3] = f2b(v4.w);
        }
    }
    __syncthreads();

    for (int idv = t; idv < 4096; idv += 256) {
        const int table = idv >> 11;
        const int rem = idv & 2047;
        const int row = rem >> 5;
        const int j   = rem & 31;
        const int qrow = qbase + row;
        const float* rp = (table == 0)
            ? rel_h + (size_t)((qrow >> 5) - j + 31) * HD_
            : rel_w + (size_t)((qrow & 31) - j + 31) * HD_;
        const float* qv = qs + row * 68;
        float acc = 0.f;
        #pragma unroll
        for (int d4 = 0; d4 < 16; ++d4) {
            float4 r4 = *(const float4*)(rp + d4 * 4);
            acc += qv[d4*4+0]*r4.x + qv[d4*4+1]*r4.y + qv[d4*4+2]*r4.z + qv[d4*4+3]*r4.w;
        }
        if (table == 0) sBH[row * 33 + j] = acc;
        else            sBW[row * 33 + j] = acc;
    }
    __syncthreads();

    f32x4 Oacc[4] = {};
    float lsum[4] = {0.f, 0.f, 0.f, 0.f};
    u16* sPw = sP + w * (16 * 72);

    for (int kt = 0; kt < 16; ++kt) {
        const int kv0 = kt * 64;
        {
            const int row = t >> 2;
            const int c0 = (t & 3) * 16;
            const u16* ksrc = kbf + ((size_t)b * HW_ + kv0 + row) * HD_ + c0;
            *(s16x8*)(sK + row * 72 + c0)     = *(const s16x8*)(ksrc);
            *(s16x8*)(sK + row * 72 + c0 + 8) = *(const s16x8*)(ksrc + 8);
            const u16* vsrc = vtb + (size_t)b * (HD_ * HW_) + (size_t)row * HW_ + kv0 + c0;
            *(s16x8*)(sVt + row * 72 + c0)     = *(const s16x8*)(vsrc);
            *(s16x8*)(sVt + row * 72 + c0 + 8) = *(const s16x8*)(vsrc + 8);
        }
        __syncthreads();

        s16x8 qa0 = *(const s16x8*)(sQ + (wq + l15) * 72 + lg * 8);
        s16x8 qa1 = *(const s16x8*)(sQ + (wq + l15) * 72 + lg * 8 + 32);
        float pf[4][4];
        #pragma unroll
        for (int nb = 0; nb < 4; ++nb) {
            s16x8 kb0 = *(const s16x8*)(sK + (nb * 16 + l15) * 72 + lg * 8);
            s16x8 kb1 = *(const s16x8*)(sK + (nb * 16 + l15) * 72 + lg * 8 + 32);
            f32x4 s = {0.f, 0.f, 0.f, 0.f};
            s = __builtin_amdgcn_mfma_f32_16x16x32_bf16(qa0, kb0, s, 0, 0, 0);
            s = __builtin_amdgcn_mfma_f32_16x16x32_bf16(qa1, kb1, s, 0, 0, 0);
            const int kv = kv0 + nb * 16 + l15;
            const int kh = kv >> 5, kw = kv & 31;
            #pragma unroll
            for (int r = 0; r < 4; ++r) {
                const int qrl = wq + lg * 4 + r;
                float p = __expf(s[r] * SCALE_ + sBH[qrl * 33 + kh] + sBW[qrl * 33 + kw]);
                lsum[r] += p;
                pf[nb][r] = p;
            }
        }

        #pragma unroll
        for (int nb = 0; nb < 4; ++nb)
            #pragma unroll
            for (int r = 0; r < 4; ++r)
                sPw[(lg * 4 + r) * 72 + nb * 16 + l15] = f2b(pf[nb][r]);
        asm volatile("" ::: "memory");

        #pragma unroll
        for (int kvh = 0; kvh < 2; ++kvh) {
            s16x8 pa = *(const s16x8*)(sPw + l15 * 72 + kvh * 32 + lg * 8);
            #pragma unroll
            for (int db = 0; db < 4; ++db) {
                s16x8 vb = *(const s16x8*)(sVt + (db * 16 + l15) * 72 + kvh * 32 + lg * 8);
                Oacc[db] = __builtin_amdgcn_mfma_f32_16x16x32_bf16(pa, vb, Oacc[db], 0, 0, 0);
            }
        }
        __syncthreads();
    }

    #pragma unroll
    for (int r = 0; r < 4; ++r) {
        float s = lsum[r];
        s += __shfl_xor(s, 1);
        s += __shfl_xor(s, 2);
        s += __shfl_xor(s, 4);
        s += __shfl_xor(s, 8);
        lsum[r] = 1.0f / s;
    }
    const int n_img = b / NH_;
    const int head  = b % NH_;
    #pragma unroll
    for (int db = 0; db < 4; ++db) {
        #pragma unroll
        for (int r = 0; r < 4; ++r) {
            const int qg = qbase + wq + lg * 4 + r;
            ob[(size_t)(n_img * HW_ + qg) * C_ + head * HD_ + db * 16 + l15] =
                f2b(Oacc[db][r] * lsum[r]);
        }
    }
}

extern "C" void kernel_launch(void* const* d_in, const int* in_sizes, int n_in,
                              void* d_out, int out_size, void* d_ws, size_t ws_size,
                              hipStream_t stream) {
    const float* x      = (const float*)d_in[0];
    const float* w_qkv  = (const float*)d_in[1];
    const float* b_qkv  = (const float*)d_in[2];
    const float* w_proj = (const float*)d_in[3];
    const float* b_proj = (const float*)d_in[4];
    const float* rel_h  = (const float*)d_in[5];
    const float* rel_w  = (const float*)d_in[6];
    float* out = (float*)d_out;

    const size_t seg = (size_t)B_ * HW_ * HD_;   // 6,291,456
    char* p = (char*)d_ws;
    u16* xb     = (u16*)p;  p += seg * 2;
    u16* wqkvT  = (u16*)p;  p += (size_t)C3_ * C_ * 2;
    u16* wprojT = (u16*)p;  p += (size_t)C_ * C_ * 2;
    float* qfp  = (float*)p; p += seg * 4;
    u16* kbf    = (u16*)p;  p += seg * 2;
    u16* vtb    = (u16*)p;  p += seg * 2;
    u16* ob     = (u16*)p;  p += seg * 2;

    cvt_bf16<<<2048, 256, 0, stream>>>(x, xb, (int)(seg / 4));
    tcvt_bf16<<<dim3(C3_ / 64, C_ / 64), 256, 0, stream>>>(w_qkv, wqkvT, C_, C3_);
    tcvt_bf16<<<dim3(C_ / 64, C_ / 64), 256, 0, stream>>>(w_proj, wprojT, C_, C_);

    gemm_qkv<<<dim3(C3_ / 128, 8192 / 128), 256, 0, stream>>>(xb, wqkvT, b_qkv, qfp, kbf, vtb);
    attn_mfma<<<dim3(HW_ / 64, B_), 256, 53760, stream>>>(qfp, kbf, vtb, rel_h, rel_w, ob);
    gemm_proj<<<dim3(C_ / 128, 8192 / 128), 256, 0, stream>>>(ob, wprojT, b_proj, out);
}

// Round 5
// 336.672 us; speedup vs baseline: 12.3976x; 1.0473x over previous
//
#include <hip/hip_runtime.h>
#include <hip/hip_bf16.h>

#define N_    8
#define H_    32
#define W_    32
#define C_    768
#define NH_   12
#define HD_   64
#define B_    96      // N_*NH_
#define HW_   1024
#define C3_   2304
#define SCALE_ 0.125f

typedef __attribute__((ext_vector_type(4))) float f32x4;
typedef __attribute__((ext_vector_type(8))) short s16x8;
typedef unsigned short u16;
typedef unsigned int u32;

__device__ inline u16 f2b(float x) {
    __hip_bfloat16 h = __float2bfloat16(x);
    return *reinterpret_cast<u16*>(&h);
}

__device__ __forceinline__ void gld_lds16(const void* g, void* l) {
    __builtin_amdgcn_global_load_lds(
        (const __attribute__((address_space(1))) u32*)g,
        (__attribute__((address_space(3))) u32*)l, 16, 0, 0);
}

// ---------------------------------------------------------------------------
// convert fp32 -> bf16 (vectorized, grid-stride)
// ---------------------------------------------------------------------------
__global__ __launch_bounds__(256) void cvt_bf16(const float* __restrict__ in,
                                                u16* __restrict__ out, int n4) {
    for (int i = blockIdx.x * blockDim.x + threadIdx.x; i < n4; i += gridDim.x * blockDim.x) {
        float4 v = ((const float4*)in)[i];
        ushort4 o;
        o.x = f2b(v.x); o.y = f2b(v.y); o.z = f2b(v.z); o.w = f2b(v.w);
        ((ushort4*)out)[i] = o;
    }
}

// ---------------------------------------------------------------------------
// transpose-convert: in [K][N] fp32 -> out [N][K] bf16, 64x64 tiles
// ---------------------------------------------------------------------------
__global__ __launch_bounds__(256) void tcvt_bf16(const float* __restrict__ in,
                                                 u16* __restrict__ out, int K, int N) {
    __shared__ u16 tile[64][72];
    const int t = threadIdx.x;
    const int k0 = blockIdx.y * 64, n0 = blockIdx.x * 64;
    const int r = t >> 2, c4 = (t & 3) * 16;
    #pragma unroll
    for (int u = 0; u < 4; ++u) {
        float4 v = *(const float4*)(in + (size_t)(k0 + r) * N + n0 + c4 + u * 4);
        tile[c4 + u*4 + 0][r] = f2b(v.x);
        tile[c4 + u*4 + 1][r] = f2b(v.y);
        tile[c4 + u*4 + 2][r] = f2b(v.z);
        tile[c4 + u*4 + 3][r] = f2b(v.w);
    }
    __syncthreads();
    #pragma unroll
    for (int u = 0; u < 2; ++u) {
        s16x8 v;
        #pragma unroll
        for (int e = 0; e < 8; ++e) v[e] = (short)tile[r][c4 + u*8 + e];
        *(s16x8*)(out + (size_t)(n0 + r) * K + k0 + c4 + u*8) = v;
    }
}

// ---------------------------------------------------------------------------
// MFMA GEMM core (m97-style): 128x128 tile, BK=32, 4 waves 2x2, double-buffered
// LDS via global_load_lds width 16, one barrier per K-step. K = 768.
// ---------------------------------------------------------------------------
#define GEMM_CORE(A_, Bt_)                                                           \
    __shared__ u16 sA[2][128 * 32];                                                  \
    __shared__ u16 sB[2][128 * 32];                                                  \
    const int t = threadIdx.x;                                                       \
    const int lane = t & 63;                                                         \
    const int w = t >> 6;                                                            \
    const int wm = w >> 1, wn = w & 1;                                               \
    const int l15 = lane & 15, lg = lane >> 4;                                       \
    const int nbase = blockIdx.x * 128;                                              \
    const int mbase = blockIdx.y * 128;                                              \
    const int srow = lane >> 2;                                                      \
    const int sslot = lane & 3;                                                      \
    const u16* gA0 = (A_) + (size_t)(mbase + w * 16 + srow) * 768 + sslot * 8;       \
    const u16* gA1 = gA0 + (size_t)64 * 768;                                         \
    const u16* gB0 = (Bt_) + (size_t)(nbase + w * 16 + srow) * 768 + sslot * 8;      \
    const u16* gB1 = gB0 + (size_t)64 * 768;                                         \
    f32x4 acc[4][4] = {};                                                            \
    gld_lds16(gA0, &sA[0][w * 512]);                                                 \
    gld_lds16(gA1, &sA[0][(w + 4) * 512]);                                           \
    gld_lds16(gB0, &sB[0][w * 512]);                                                 \
    gld_lds16(gB1, &sB[0][(w + 4) * 512]);                                           \
    for (int kt = 0; kt < 24; ++kt) {                                                \
        const int p = kt & 1;                                                        \
        __syncthreads();                                                             \
        if (kt < 23) {                                                               \
            const int kb = (kt + 1) * 32;                                            \
            gld_lds16(gA0 + kb, &sA[p ^ 1][w * 512]);                                \
            gld_lds16(gA1 + kb, &sA[p ^ 1][(w + 4) * 512]);                          \
            gld_lds16(gB0 + kb, &sB[p ^ 1][w * 512]);                                \
            gld_lds16(gB1 + kb, &sB[p ^ 1][(w + 4) * 512]);                          \
        }                                                                            \
        const u16* pa = &sA[p][(wm * 64 + l15) * 32 + lg * 8];                       \
        const u16* pb = &sB[p][(wn * 64 + l15) * 32 + lg * 8];                       \
        s16x8 afr[4], bfr[4];                                                        \
        _Pragma("unroll")                                                            \
        for (int i = 0; i < 4; ++i) {                                                \
            afr[i] = *(const s16x8*)(pa + i * 512);                                  \
            bfr[i] = *(const s16x8*)(pb + i * 512);                                  \
        }                                                                            \
        _Pragma("unroll")                                                            \
        for (int i = 0; i < 4; ++i)                                                  \
            _Pragma("unroll")                                                        \
            for (int j = 0; j < 4; ++j)                                              \
                acc[i][j] = __builtin_amdgcn_mfma_f32_16x16x32_bf16(afr[i], bfr[j],  \
                                                                    acc[i][j], 0, 0, 0); \
    }

__global__ __launch_bounds__(256) void gemm_qkv(const u16* __restrict__ A,
                                                const u16* __restrict__ Bt,
                                                const float* __restrict__ bias,
                                                float* __restrict__ qout,
                                                u16* __restrict__ kout,
                                                u16* __restrict__ vout) {
    GEMM_CORE(A, Bt)
    const int which = nbase / C_;
    const int head  = ((nbase % C_) >> 6) + wn;
    const int mrow0 = mbase + wm * 64 + lg * 4;
    #pragma unroll
    for (int i = 0; i < 4; ++i) {
        #pragma unroll
        for (int r = 0; r < 4; ++r) {
            const int m = mrow0 + i * 16 + r;
            const size_t bidx = (size_t)((m >> 10) * NH_ + head);
            const int pp = m & 1023;
            #pragma unroll
            for (int j = 0; j < 4; ++j) {
                const int d = j * 16 + l15;
                const float val = acc[i][j][r] + bias[nbase + wn * 64 + d];
                if (which == 0)      qout[(bidx * HW_ + pp) * HD_ + d] = val;
                else if (which == 1) kout[(bidx * HW_ + pp) * HD_ + d] = f2b(val);
                else                 vout[bidx * (size_t)(HW_ * HD_) + (size_t)d * HW_ + pp] = f2b(val);
            }
        }
    }
}

__global__ __launch_bounds__(256) void gemm_proj(const u16* __restrict__ A,
                                                 const u16* __restrict__ Bt,
                                                 const float* __restrict__ bias,
                                                 float* __restrict__ out) {
    GEMM_CORE(A, Bt)
    const int mrow0 = mbase + wm * 64 + lg * 4;
    #pragma unroll
    for (int i = 0; i < 4; ++i) {
        #pragma unroll
        for (int r = 0; r < 4; ++r) {
            const int m = mrow0 + i * 16 + r;
            #pragma unroll
            for (int j = 0; j < 4; ++j) {
                const int n = nbase + wn * 64 + j * 16 + l15;
                out[(size_t)m * C_ + n] = acc[i][j][r] + bias[n];
            }
        }
    }
}

// ---------------------------------------------------------------------------
// Kernel: MFMA bf16 flash rel-pos attention, reg-staged async pipeline (T14).
// Per block: one b, 64 q rows, 4 waves (16 q rows each), 16 KV tiles of 64.
// K/V staged global->VGPR (issued one compute phase early)->ds_write_b128 into
// PADDED [64][72] tiles (round-3-verified layout). 2 barriers/iter:
//   iter kt: issue K(kt+1)->regs | QK^T reads sK(kt) | write V(kt) regs->sVt
//            B1 | write K(kt+1)->sK; issue V(kt+1)->regs | P->sPw | PV reads sVt
//            B2
// LDS map (bytes): sK[0,9216) sVt[9216,18432) sP[18432,27648)
//   sQ[27648,36864) sBHT[36864,45568) sBWT[45568,54272)
//   qs f32 [64][68] @0 (prologue only, overlaps sK/sVt). total 54272 -> 3 blk/CU.
// ---------------------------------------------------------------------------
__global__ __launch_bounds__(256) void attn_mfma(const float* __restrict__ qf,
                                                 const u16* __restrict__ kbf,
                                                 const u16* __restrict__ vtb,
                                                 const float* __restrict__ rel_h,
                                                 const float* __restrict__ rel_w,
                                                 u16* __restrict__ ob) {
    extern __shared__ char smem[];
    u16*   sK   = (u16*)smem;                 // [64][72]
    u16*   sVt  = (u16*)(smem + 9216);        // [64][72]
    u16*   sP   = (u16*)(smem + 18432);       // 4 x [16][72]
    u16*   sQ   = (u16*)(smem + 27648);       // [64][72]
    float* sBHT = (float*)(smem + 36864);     // [32 kh][68 row]
    float* sBWT = (float*)(smem + 45568);     // [32 kw][68 row]
    float* qs   = (float*)smem;               // [64][68] fp32 (prologue only)

    const int t = threadIdx.x;
    const int lane = t & 63;
    const int w = t >> 6;
    const int l15 = lane & 15;
    const int lg  = lane >> 4;
    const int wq  = w * 16;
    const int b = blockIdx.y;
    const int qbase = blockIdx.x * 64;

    // ---- prologue: Q -> qs (fp32) + sQ (bf16, pre-scaled by SCALE_)
    {
        const int row = t >> 2;
        const int c0 = (t & 3) * 16;
        const float* src = qf + ((size_t)b * HW_ + qbase + row) * HD_ + c0;
        #pragma unroll
        for (int u = 0; u < 4; ++u) {
            float4 v4 = *(const float4*)(src + u * 4);
            float* qd = qs + row * 68 + c0 + u * 4;
            qd[0] = v4.x; qd[1] = v4.y; qd[2] = v4.z; qd[3] = v4.w;
            u16* qb = sQ + row * 72 + c0 + u * 4;
            qb[0] = f2b(v4.x * SCALE_); qb[1] = f2b(v4.y * SCALE_);
            qb[2] = f2b(v4.z * SCALE_); qb[3] = f2b(v4.w * SCALE_);
        }
    }
    __syncthreads();

    // ---- bias tables, TRANSPOSED: sBHT[kh][row], sBWT[kw][row] (fp32, exact)
    for (int idv = t; idv < 4096; idv += 256) {
        const int table = idv >> 11;
        const int rem = idv & 2047;
        const int row = rem >> 5;
        const int j   = rem & 31;
        const int qrow = qbase + row;
        const float* rp = (table == 0)
            ? rel_h + (size_t)((qrow >> 5) - j + 31) * HD_
            : rel_w + (size_t)((qrow & 31) - j + 31) * HD_;
        const float* qv = qs + row * 68;
        float acc = 0.f;
        #pragma unroll
        for (int d4 = 0; d4 < 16; ++d4) {
            float4 r4 = *(const float4*)(rp + d4 * 4);
            acc += qv[d4*4+0]*r4.x + qv[d4*4+1]*r4.y + qv[d4*4+2]*r4.z + qv[d4*4+3]*r4.w;
        }
        if (table == 0) sBHT[j * 68 + row] = acc;
        else            sBWT[j * 68 + row] = acc;
    }
    __syncthreads();    // qs dead; sK/sVt may be written from here on

    // ---- hoisted fragments / bias registers
    s16x8 qa0 = *(const s16x8*)(sQ + (wq + l15) * 72 + lg * 8);
    s16x8 qa1 = *(const s16x8*)(sQ + (wq + l15) * 72 + lg * 8 + 32);
    f32x4 bwlo = *(const f32x4*)(sBWT + l15 * 68 + wq + lg * 4);
    f32x4 bwhi = *(const f32x4*)(sBWT + (l15 + 16) * 68 + wq + lg * 4);

    // ---- staging geometry (round-3 layout: thread t -> row t>>2, cols (t&3)*16..+16)
    const int srow = t >> 2;
    const int sc0  = (t & 3) * 16;
    const u16* kg = kbf + (size_t)b * HW_ * HD_ + (size_t)srow * HD_ + sc0;  // +kv0*HD_
    const u16* vg = vtb + (size_t)b * HD_ * HW_ + (size_t)srow * HW_ + sc0;  // +kv0
    u16* skw = sK  + srow * 72 + sc0;
    u16* svw = sVt + srow * 72 + sc0;

    // ---- preload tile 0: K(0) -> LDS now; V(0) stays in regs until iter 0
    s16x8 kr0 = *(const s16x8*)(kg);
    s16x8 kr1 = *(const s16x8*)(kg + 8);
    s16x8 vr0 = *(const s16x8*)(vg);
    s16x8 vr1 = *(const s16x8*)(vg + 8);
    *(s16x8*)(skw)     = kr0;
    *(s16x8*)(skw + 8) = kr1;
    __syncthreads();   // sK(0) ready

    f32x4 Oacc[4] = {};
    float lsum[4] = {0.f, 0.f, 0.f, 0.f};
    u16* sPw = sP + w * (16 * 72);

    for (int kt = 0; kt < 16; ++kt) {
        // ---- issue K(kt+1) global loads (consumed after B1)
        if (kt < 15) {
            const u16* kn = kg + (size_t)(kt + 1) * 64 * HD_;
            kr0 = *(const s16x8*)(kn);
            kr1 = *(const s16x8*)(kn + 8);
        }

        // ---- QK^T + bias + exp (reads sK(kt))
        f32x4 bh0 = *(const f32x4*)(sBHT + (2 * kt) * 68 + wq + lg * 4);
        f32x4 bh1 = *(const f32x4*)(sBHT + (2 * kt + 1) * 68 + wq + lg * 4);
        float pf[4][4];
        #pragma unroll
        for (int nb = 0; nb < 4; ++nb) {
            const u16* kp = sK + (nb * 16 + l15) * 72 + lg * 8;
            s16x8 kf0 = *(const s16x8*)(kp);
            s16x8 kf1 = *(const s16x8*)(kp + 32);
            f32x4 s = {0.f, 0.f, 0.f, 0.f};
            s = __builtin_amdgcn_mfma_f32_16x16x32_bf16(qa0, kf0, s, 0, 0, 0);
            s = __builtin_amdgcn_mfma_f32_16x16x32_bf16(qa1, kf1, s, 0, 0, 0);
            const f32x4 bh = (nb >> 1) ? bh1 : bh0;
            const f32x4 bw = (nb & 1) ? bwhi : bwlo;
            #pragma unroll
            for (int r = 0; r < 4; ++r) {
                float p = __expf(s[r] + bh[r] + bw[r]);
                lsum[r] += p;
                pf[nb][r] = p;
            }
        }

        // ---- write V(kt) regs -> sVt (sVt free since B2 of previous iter)
        *(s16x8*)(svw)     = vr0;
        *(s16x8*)(svw + 8) = vr1;
        __syncthreads();   // B1: sVt(kt) visible; all waves done reading sK(kt)

        // ---- write K(kt+1) -> sK; issue V(kt+1) loads
        if (kt < 15) {
            *(s16x8*)(skw)     = kr0;
            *(s16x8*)(skw + 8) = kr1;
            const u16* vn = vg + (size_t)(kt + 1) * 64;
            vr0 = *(const s16x8*)(vn);
            vr1 = *(const s16x8*)(vn + 8);
        }

        // ---- P tile -> wave-private LDS (bf16)
        #pragma unroll
        for (int nb = 0; nb < 4; ++nb)
            #pragma unroll
            for (int r = 0; r < 4; ++r)
                sPw[(lg * 4 + r) * 72 + nb * 16 + l15] = f2b(pf[nb][r]);
        asm volatile("" ::: "memory");

        // ---- O += P V (reads sVt(kt), sPw)
        #pragma unroll
        for (int kvh = 0; kvh < 2; ++kvh) {
            s16x8 pa = *(const s16x8*)(sPw + l15 * 72 + kvh * 32 + lg * 8);
            #pragma unroll
            for (int db = 0; db < 4; ++db) {
                s16x8 vb = *(const s16x8*)(sVt + (db * 16 + l15) * 72 + kvh * 32 + lg * 8);
                Oacc[db] = __builtin_amdgcn_mfma_f32_16x16x32_bf16(pa, vb, Oacc[db], 0, 0, 0);
            }
        }
        __syncthreads();   // B2: sK(kt+1) visible; all waves done reading sVt(kt)
    }

    // ---- epilogue
    #pragma unroll
    for (int r = 0; r < 4; ++r) {
        float s = lsum[r];
        s += __shfl_xor(s, 1);
        s += __shfl_xor(s, 2);
        s += __shfl_xor(s, 4);
        s += __shfl_xor(s, 8);
        lsum[r] = 1.0f / s;
    }
    const int n_img = b / NH_;
    const int head  = b % NH_;
    #pragma unroll
    for (int db = 0; db < 4; ++db) {
        #pragma unroll
        for (int r = 0; r < 4; ++r) {
            const int qg = qbase + wq + lg * 4 + r;
            ob[(size_t)(n_img * HW_ + qg) * C_ + head * HD_ + db * 16 + l15] =
                f2b(Oacc[db][r] * lsum[r]);
        }
    }
}

extern "C" void kernel_launch(void* const* d_in, const int* in_sizes, int n_in,
                              void* d_out, int out_size, void* d_ws, size_t ws_size,
                              hipStream_t stream) {
    const float* x      = (const float*)d_in[0];
    const float* w_qkv  = (const float*)d_in[1];
    const float* b_qkv  = (const float*)d_in[2];
    const float* w_proj = (const float*)d_in[3];
    const float* b_proj = (const float*)d_in[4];
    const float* rel_h  = (const float*)d_in[5];
    const float* rel_w  = (const float*)d_in[6];
    float* out = (float*)d_out;

    const size_t seg = (size_t)B_ * HW_ * HD_;   // 6,291,456
    char* p = (char*)d_ws;
    u16* xb     = (u16*)p;  p += seg * 2;
    u16* wqkvT  = (u16*)p;  p += (size_t)C3_ * C_ * 2;
    u16* wprojT = (u16*)p;  p += (size_t)C_ * C_ * 2;
    float* qfp  = (float*)p; p += seg * 4;
    u16* kbf    = (u16*)p;  p += seg * 2;
    u16* vtb    = (u16*)p;  p += seg * 2;
    u16* ob     = (u16*)p;  p += seg * 2;

    cvt_bf16<<<2048, 256, 0, stream>>>(x, xb, (int)(seg / 4));
    tcvt_bf16<<<dim3(C3_ / 64, C_ / 64), 256, 0, stream>>>(w_qkv, wqkvT, C_, C3_);
    tcvt_bf16<<<dim3(C_ / 64, C_ / 64), 256, 0, stream>>>(w_proj, wprojT, C_, C_);

    gemm_qkv<<<dim3(C3_ / 128, 8192 / 128), 256, 0, stream>>>(xb, wqkvT, b_qkv, qfp, kbf, vtb);
    attn_mfma<<<dim3(HW_ / 64, B_), 256, 54272, stream>>>(qfp, kbf, vtb, rel_h, rel_w, ob);
    gemm_proj<<<dim3(C_ / 128, 8192 / 128), 256, 0, stream>>>(ob, wprojT, b_proj, out);
}

// Round 6
// 323.535 us; speedup vs baseline: 12.9010x; 1.0406x over previous
//
#include <hip/hip_runtime.h>
#include <hip/hip_bf16.h>

#define N_    8
#define H_    32
#define W_    32
#define C_    768
#define NH_   12
#define HD_   64
#define B_    96      // N_*NH_
#define HW_   1024
#define C3_   2304
#define SCALE_ 0.125f

typedef __attribute__((ext_vector_type(4))) float f32x4;
typedef __attribute__((ext_vector_type(8))) short s16x8;
typedef __attribute__((ext_vector_type(2))) unsigned int u32x2;
typedef unsigned short u16;
typedef unsigned int u32;

__device__ inline u16 f2b(float x) {
    __hip_bfloat16 h = __float2bfloat16(x);
    return *reinterpret_cast<u16*>(&h);
}

__device__ __forceinline__ void gld_lds16(const void* g, void* l) {
    __builtin_amdgcn_global_load_lds(
        (const __attribute__((address_space(1))) u32*)g,
        (__attribute__((address_space(3))) u32*)l, 16, 0, 0);
}

// ---------------------------------------------------------------------------
// convert fp32 -> bf16 (vectorized, grid-stride)
// ---------------------------------------------------------------------------
__global__ __launch_bounds__(256) void cvt_bf16(const float* __restrict__ in,
                                                u16* __restrict__ out, int n4) {
    for (int i = blockIdx.x * blockDim.x + threadIdx.x; i < n4; i += gridDim.x * blockDim.x) {
        float4 v = ((const float4*)in)[i];
        ushort4 o;
        o.x = f2b(v.x); o.y = f2b(v.y); o.z = f2b(v.z); o.w = f2b(v.w);
        ((ushort4*)out)[i] = o;
    }
}

// ---------------------------------------------------------------------------
// transpose-convert: in [K][N] fp32 -> out [N][K] bf16, 64x64 tiles
// ---------------------------------------------------------------------------
__global__ __launch_bounds__(256) void tcvt_bf16(const float* __restrict__ in,
                                                 u16* __restrict__ out, int K, int N) {
    __shared__ u16 tile[64][72];
    const int t = threadIdx.x;
    const int k0 = blockIdx.y * 64, n0 = blockIdx.x * 64;
    const int r = t >> 2, c4 = (t & 3) * 16;
    #pragma unroll
    for (int u = 0; u < 4; ++u) {
        float4 v = *(const float4*)(in + (size_t)(k0 + r) * N + n0 + c4 + u * 4);
        tile[c4 + u*4 + 0][r] = f2b(v.x);
        tile[c4 + u*4 + 1][r] = f2b(v.y);
        tile[c4 + u*4 + 2][r] = f2b(v.z);
        tile[c4 + u*4 + 3][r] = f2b(v.w);
    }
    __syncthreads();
    #pragma unroll
    for (int u = 0; u < 2; ++u) {
        s16x8 v;
        #pragma unroll
        for (int e = 0; e < 8; ++e) v[e] = (short)tile[r][c4 + u*8 + e];
        *(s16x8*)(out + (size_t)(n0 + r) * K + k0 + c4 + u*8) = v;
    }
}

// ---------------------------------------------------------------------------
// MFMA GEMM core (m97-style): 128x128 tile, BK=32, 4 waves 2x2, double-buffered
// LDS via global_load_lds width 16, one barrier per K-step. K = 768.
// ---------------------------------------------------------------------------
#define GEMM_CORE(A_, Bt_)                                                           \
    __shared__ u16 sA[2][128 * 32];                                                  \
    __shared__ u16 sB[2][128 * 32];                                                  \
    const int t = threadIdx.x;                                                       \
    const int lane = t & 63;                                                         \
    const int w = t >> 6;                                                            \
    const int wm = w >> 1, wn = w & 1;                                               \
    const int l15 = lane & 15, lg = lane >> 4;                                       \
    const int nbase = blockIdx.x * 128;                                              \
    const int mbase = blockIdx.y * 128;                                              \
    const int srow = lane >> 2;                                                      \
    const int sslot = lane & 3;                                                      \
    const u16* gA0 = (A_) + (size_t)(mbase + w * 16 + srow) * 768 + sslot * 8;       \
    const u16* gA1 = gA0 + (size_t)64 * 768;                                         \
    const u16* gB0 = (Bt_) + (size_t)(nbase + w * 16 + srow) * 768 + sslot * 8;      \
    const u16* gB1 = gB0 + (size_t)64 * 768;                                         \
    f32x4 acc[4][4] = {};                                                            \
    gld_lds16(gA0, &sA[0][w * 512]);                                                 \
    gld_lds16(gA1, &sA[0][(w + 4) * 512]);                                           \
    gld_lds16(gB0, &sB[0][w * 512]);                                                 \
    gld_lds16(gB1, &sB[0][(w + 4) * 512]);                                           \
    for (int kt = 0; kt < 24; ++kt) {                                                \
        const int p = kt & 1;                                                        \
        __syncthreads();                                                             \
        if (kt < 23) {                                                               \
            const int kb = (kt + 1) * 32;                                            \
            gld_lds16(gA0 + kb, &sA[p ^ 1][w * 512]);                                \
            gld_lds16(gA1 + kb, &sA[p ^ 1][(w + 4) * 512]);                          \
            gld_lds16(gB0 + kb, &sB[p ^ 1][w * 512]);                                \
            gld_lds16(gB1 + kb, &sB[p ^ 1][(w + 4) * 512]);                          \
        }                                                                            \
        const u16* pa = &sA[p][(wm * 64 + l15) * 32 + lg * 8];                       \
        const u16* pb = &sB[p][(wn * 64 + l15) * 32 + lg * 8];                       \
        s16x8 afr[4], bfr[4];                                                        \
        _Pragma("unroll")                                                            \
        for (int i = 0; i < 4; ++i) {                                                \
            afr[i] = *(const s16x8*)(pa + i * 512);                                  \
            bfr[i] = *(const s16x8*)(pb + i * 512);                                  \
        }                                                                            \
        _Pragma("unroll")                                                            \
        for (int i = 0; i < 4; ++i)                                                  \
            _Pragma("unroll")                                                        \
            for (int j = 0; j < 4; ++j)                                              \
                acc[i][j] = __builtin_amdgcn_mfma_f32_16x16x32_bf16(afr[i], bfr[j],  \
                                                                    acc[i][j], 0, 0, 0); \
    }

__global__ __launch_bounds__(256) void gemm_qkv(const u16* __restrict__ A,
                                                const u16* __restrict__ Bt,
                                                const float* __restrict__ bias,
                                                float* __restrict__ qout,
                                                u16* __restrict__ kout,
                                                u16* __restrict__ vout) {
    GEMM_CORE(A, Bt)
    const int which = nbase / C_;
    const int head  = ((nbase % C_) >> 6) + wn;
    const int mrow0 = mbase + wm * 64 + lg * 4;
    #pragma unroll
    for (int i = 0; i < 4; ++i) {
        #pragma unroll
        for (int r = 0; r < 4; ++r) {
            const int m = mrow0 + i * 16 + r;
            const size_t bidx = (size_t)((m >> 10) * NH_ + head);
            const int pp = m & 1023;
            #pragma unroll
            for (int j = 0; j < 4; ++j) {
                const int d = j * 16 + l15;
                const float val = acc[i][j][r] + bias[nbase + wn * 64 + d];
                if (which == 0)      qout[(bidx * HW_ + pp) * HD_ + d] = val;
                else if (which == 1) kout[(bidx * HW_ + pp) * HD_ + d] = f2b(val);
                else                 vout[bidx * (size_t)(HW_ * HD_) + (size_t)d * HW_ + pp] = f2b(val);
            }
        }
    }
}

__global__ __launch_bounds__(256) void gemm_proj(const u16* __restrict__ A,
                                                 const u16* __restrict__ Bt,
                                                 const float* __restrict__ bias,
                                                 float* __restrict__ out) {
    GEMM_CORE(A, Bt)
    const int mrow0 = mbase + wm * 64 + lg * 4;
    #pragma unroll
    for (int i = 0; i < 4; ++i) {
        #pragma unroll
        for (int r = 0; r < 4; ++r) {
            const int m = mrow0 + i * 16 + r;
            #pragma unroll
            for (int j = 0; j < 4; ++j) {
                const int n = nbase + wn * 64 + j * 16 + l15;
                out[(size_t)m * C_ + n] = acc[i][j][r] + bias[n];
            }
        }
    }
}

// ---------------------------------------------------------------------------
// Kernel: MFMA bf16 flash rel-pos attention, swapped-QK^T lane-local P rows.
// Per block: one b, 64 q rows, 4 waves (16 q rows each), 16 KV tiles of 64.
//
// QK^T computed SWAPPED: s = mfma(K_frag, Q_frag) -> S^T tile, so lane
// (lg,l15) holds S[q = wq+l15][kv = nb*16 + lg*4 + r].  Consecutive r =
// consecutive kv -> P-store to LDS is 4x ds_write_b64 (conflict-free, 2-way)
// instead of 16 scalar b16 writes; PV-side P read is unchanged from the
// verified round-3/5 path.  Bias: bw hoisted out of the loop (2x f32x4 per
// lane), bh = 2 broadcast scalars per iter.  lsum is per-lane (one q row);
// reduced via shfl_xor(16,32), redistributed via width-16 shfl for epilogue.
// Q fragments loaded directly from global (sQ eliminated).
// Reg-staged async K/V pipeline kept from round 5 (2 barriers/iter).
//
// LDS map (bytes): sK[0,9216) sVt[9216,18432) sP[18432,27648)
//   sBH[27648,36864) [64][36]f32  sBW[36864,46080) [64][36]f32
//   qs f32 [64][68]=17408 @0 (prologue only, overlaps sK/sVt).
// total 46080 -> 3 blocks/CU.
// ---------------------------------------------------------------------------
__global__ __launch_bounds__(256) void attn_mfma(const float* __restrict__ qf,
                                                 const u16* __restrict__ kbf,
                                                 const u16* __restrict__ vtb,
                                                 const float* __restrict__ rel_h,
                                                 const float* __restrict__ rel_w,
                                                 u16* __restrict__ ob) {
    extern __shared__ char smem[];
    u16*   sK  = (u16*)smem;                  // [64][72]
    u16*   sVt = (u16*)(smem + 9216);         // [64][72]
    u16*   sP  = (u16*)(smem + 18432);        // 4 x [16][72]
    float* sBH = (float*)(smem + 27648);      // [64][36]
    float* sBW = (float*)(smem + 36864);      // [64][36]
    float* qs  = (float*)smem;                // [64][68] fp32 (prologue only)

    const int t = threadIdx.x;
    const int lane = t & 63;
    const int w = t >> 6;
    const int l15 = lane & 15;
    const int lg  = lane >> 4;
    const int wq  = w * 16;
    const int b = blockIdx.y;
    const int qbase = blockIdx.x * 64;

    // ---- prologue: Q -> qs (fp32, for exact bias dot-products)
    {
        const int row = t >> 2;
        const int c0 = (t & 3) * 16;
        const float* src = qf + ((size_t)b * HW_ + qbase + row) * HD_ + c0;
        #pragma unroll
        for (int u = 0; u < 4; ++u) {
            float4 v4 = *(const float4*)(src + u * 4);
            float* qd = qs + row * 68 + c0 + u * 4;
            qd[0] = v4.x; qd[1] = v4.y; qd[2] = v4.z; qd[3] = v4.w;
        }
    }

    // ---- Q fragments straight from global (bf16, pre-scaled by SCALE_)
    s16x8 qa0, qa1;
    {
        const float* qrow = qf + ((size_t)b * HW_ + qbase + wq + l15) * HD_;
        float4 a0 = *(const float4*)(qrow + lg * 8);
        float4 a1 = *(const float4*)(qrow + lg * 8 + 4);
        float4 b0 = *(const float4*)(qrow + 32 + lg * 8);
        float4 b1 = *(const float4*)(qrow + 32 + lg * 8 + 4);
        qa0[0] = (short)f2b(a0.x * SCALE_); qa0[1] = (short)f2b(a0.y * SCALE_);
        qa0[2] = (short)f2b(a0.z * SCALE_); qa0[3] = (short)f2b(a0.w * SCALE_);
        qa0[4] = (short)f2b(a1.x * SCALE_); qa0[5] = (short)f2b(a1.y * SCALE_);
        qa0[6] = (short)f2b(a1.z * SCALE_); qa0[7] = (short)f2b(a1.w * SCALE_);
        qa1[0] = (short)f2b(b0.x * SCALE_); qa1[1] = (short)f2b(b0.y * SCALE_);
        qa1[2] = (short)f2b(b0.z * SCALE_); qa1[3] = (short)f2b(b0.w * SCALE_);
        qa1[4] = (short)f2b(b1.x * SCALE_); qa1[5] = (short)f2b(b1.y * SCALE_);
        qa1[6] = (short)f2b(b1.z * SCALE_); qa1[7] = (short)f2b(b1.w * SCALE_);
    }
    __syncthreads();   // qs ready

    // ---- bias tables, row-major padded: sBH[row][36], sBW[row][36]
    for (int idv = t; idv < 4096; idv += 256) {
        const int table = idv >> 11;
        const int rem = idv & 2047;
        const int row = rem >> 5;
        const int j   = rem & 31;
        const int qrow = qbase + row;
        const float* rp = (table == 0)
            ? rel_h + (size_t)((qrow >> 5) - j + 31) * HD_
            : rel_w + (size_t)((qrow & 31) - j + 31) * HD_;
        const float* qv = qs + row * 68;
        float acc = 0.f;
        #pragma unroll
        for (int d4 = 0; d4 < 16; ++d4) {
            float4 r4 = *(const float4*)(rp + d4 * 4);
            acc += qv[d4*4+0]*r4.x + qv[d4*4+1]*r4.y + qv[d4*4+2]*r4.z + qv[d4*4+3]*r4.w;
        }
        if (table == 0) sBH[row * 36 + j] = acc;
        else            sBW[row * 36 + j] = acc;
    }
    __syncthreads();    // qs dead; sK/sVt/sP may be written from here on

    // ---- hoisted bias registers (this lane's q row = wq + l15)
    const f32x4 bwE = *(const f32x4*)(sBW + (wq + l15) * 36 + lg * 4);
    const f32x4 bwO = *(const f32x4*)(sBW + (wq + l15) * 36 + 16 + lg * 4);

    // ---- staging geometry (round-3 layout: thread t -> row t>>2, cols (t&3)*16)
    const int srow = t >> 2;
    const int sc0  = (t & 3) * 16;
    const u16* kg = kbf + (size_t)b * HW_ * HD_ + (size_t)srow * HD_ + sc0;  // +kv0*HD_
    const u16* vg = vtb + (size_t)b * HD_ * HW_ + (size_t)srow * HW_ + sc0;  // +kv0
    u16* skw = sK  + srow * 72 + sc0;
    u16* svw = sVt + srow * 72 + sc0;

    // ---- preload tile 0: K(0) -> LDS now; V(0) stays in regs until iter 0
    s16x8 kr0 = *(const s16x8*)(kg);
    s16x8 kr1 = *(const s16x8*)(kg + 8);
    s16x8 vr0 = *(const s16x8*)(vg);
    s16x8 vr1 = *(const s16x8*)(vg + 8);
    *(s16x8*)(skw)     = kr0;
    *(s16x8*)(skw + 8) = kr1;
    __syncthreads();   // sK(0) ready

    f32x4 Oacc[4] = {};
    float lsum = 0.f;
    u16* sPw = sP + w * (16 * 72);

    for (int kt = 0; kt < 16; ++kt) {
        // ---- issue K(kt+1) global loads (consumed after B1)
        if (kt < 15) {
            const u16* kn = kg + (size_t)(kt + 1) * 64 * HD_;
            kr0 = *(const s16x8*)(kn);
            kr1 = *(const s16x8*)(kn + 8);
        }

        // ---- per-iter bias scalars: kh = 2*kt + (nb>>1)
        const float bhA = sBH[(wq + l15) * 36 + 2 * kt];
        const float bhB = sBH[(wq + l15) * 36 + 2 * kt + 1];

        // ---- S^T = K Q^T (swapped): lane holds S[q=wq+l15][kv=nb*16+lg*4+r]
        float pf[4][4];
        #pragma unroll
        for (int nb = 0; nb < 4; ++nb) {
            const u16* kp = sK + (nb * 16 + l15) * 72 + lg * 8;
            s16x8 kf0 = *(const s16x8*)(kp);
            s16x8 kf1 = *(const s16x8*)(kp + 32);
            f32x4 s = {0.f, 0.f, 0.f, 0.f};
            s = __builtin_amdgcn_mfma_f32_16x16x32_bf16(kf0, qa0, s, 0, 0, 0);
            s = __builtin_amdgcn_mfma_f32_16x16x32_bf16(kf1, qa1, s, 0, 0, 0);
            const float bh = (nb >> 1) ? bhB : bhA;
            const f32x4 bw = (nb & 1) ? bwO : bwE;
            #pragma unroll
            for (int r = 0; r < 4; ++r) {
                float p = __expf(s[r] + bh + bw[r]);
                lsum += p;
                pf[nb][r] = p;
            }
        }

        // ---- write V(kt) regs -> sVt (sVt free since B2 of previous iter)
        *(s16x8*)(svw)     = vr0;
        *(s16x8*)(svw + 8) = vr1;
        __syncthreads();   // B1: sVt(kt) visible; all waves done reading sK(kt)

        // ---- write K(kt+1) -> sK; issue V(kt+1) loads
        if (kt < 15) {
            *(s16x8*)(skw)     = kr0;
            *(s16x8*)(skw + 8) = kr1;
            const u16* vn = vg + (size_t)(kt + 1) * 64;
            vr0 = *(const s16x8*)(vn);
            vr1 = *(const s16x8*)(vn + 8);
        }

        // ---- P tile -> wave-private LDS: row q=l15, 4 consecutive kv per b64
        #pragma unroll
        for (int nb = 0; nb < 4; ++nb) {
            u32x2 pw;
            pw.x = (u32)f2b(pf[nb][0]) | ((u32)f2b(pf[nb][1]) << 16);
            pw.y = (u32)f2b(pf[nb][2]) | ((u32)f2b(pf[nb][3]) << 16);
            *(u32x2*)(sPw + l15 * 72 + nb * 16 + lg * 4) = pw;
        }
        asm volatile("" ::: "memory");

        // ---- O += P V (reads sVt(kt), sPw; P read identical to round 3/5)
        #pragma unroll
        for (int kvh = 0; kvh < 2; ++kvh) {
            s16x8 pa = *(const s16x8*)(sPw + l15 * 72 + kvh * 32 + lg * 8);
            #pragma unroll
            for (int db = 0; db < 4; ++db) {
                s16x8 vb = *(const s16x8*)(sVt + (db * 16 + l15) * 72 + kvh * 32 + lg * 8);
                Oacc[db] = __builtin_amdgcn_mfma_f32_16x16x32_bf16(pa, vb, Oacc[db], 0, 0, 0);
            }
        }
        __syncthreads();   // B2: sK(kt+1) visible; all waves done reading sVt(kt)
    }

    // ---- epilogue: lane's lsum is a partial for q = wq+l15
    float lsumF = lsum;
    lsumF += __shfl_xor(lsumF, 16);
    lsumF += __shfl_xor(lsumF, 32);   // now full row-sum of q=wq+l15 on every lane
    float linv[4];
    #pragma unroll
    for (int r = 0; r < 4; ++r)
        linv[r] = 1.0f / __shfl(lsumF, lg * 4 + r, 16);   // row sum for q=wq+lg*4+r

    const int n_img = b / NH_;
    const int head  = b % NH_;
    #pragma unroll
    for (int db = 0; db < 4; ++db) {
        #pragma unroll
        for (int r = 0; r < 4; ++r) {
            const int qg = qbase + wq + lg * 4 + r;
            ob[(size_t)(n_img * HW_ + qg) * C_ + head * HD_ + db * 16 + l15] =
                f2b(Oacc[db][r] * linv[r]);
        }
    }
}

extern "C" void kernel_launch(void* const* d_in, const int* in_sizes, int n_in,
                              void* d_out, int out_size, void* d_ws, size_t ws_size,
                              hipStream_t stream) {
    const float* x      = (const float*)d_in[0];
    const float* w_qkv  = (const float*)d_in[1];
    const float* b_qkv  = (const float*)d_in[2];
    const float* w_proj = (const float*)d_in[3];
    const float* b_proj = (const float*)d_in[4];
    const float* rel_h  = (const float*)d_in[5];
    const float* rel_w  = (const float*)d_in[6];
    float* out = (float*)d_out;

    const size_t seg = (size_t)B_ * HW_ * HD_;   // 6,291,456
    char* p = (char*)d_ws;
    u16* xb     = (u16*)p;  p += seg * 2;
    u16* wqkvT  = (u16*)p;  p += (size_t)C3_ * C_ * 2;
    u16* wprojT = (u16*)p;  p += (size_t)C_ * C_ * 2;
    float* qfp  = (float*)p; p += seg * 4;
    u16* kbf    = (u16*)p;  p += seg * 2;
    u16* vtb    = (u16*)p;  p += seg * 2;
    u16* ob     = (u16*)p;  p += seg * 2;

    cvt_bf16<<<2048, 256, 0, stream>>>(x, xb, (int)(seg / 4));
    tcvt_bf16<<<dim3(C3_ / 64, C_ / 64), 256, 0, stream>>>(w_qkv, wqkvT, C_, C3_);
    tcvt_bf16<<<dim3(C_ / 64, C_ / 64), 256, 0, stream>>>(w_proj, wprojT, C_, C_);

    gemm_qkv<<<dim3(C3_ / 128, 8192 / 128), 256, 0, stream>>>(xb, wqkvT, b_qkv, qfp, kbf, vtb);
    attn_mfma<<<dim3(HW_ / 64, B_), 256, 46080, stream>>>(qfp, kbf, vtb, rel_h, rel_w, ob);
    gemm_proj<<<dim3(C_ / 128, 8192 / 128), 256, 0, stream>>>(ob, wprojT, b_proj, out);
}